// Round 17
// baseline (160.709 us; speedup 1.0000x reference)
//
#include <hip/hip_runtime.h>

#define N_NODES 100000
#define N_EDGES 1600000
#define IN_FEAT 128
#define OUT_FEAT 64
#define SLOPE 0.22916666666666666f  // (1/8 + 1/3)/2 = 11/48

#define NPB 128            // nodes per bucket
#define NB 782             // ceil(N_NODES / NPB)
#define CAP 2560           // static bucket capacity (mean 2046 -> 11+ sigma margin)
#define BIN_CHUNK 8192     // edges per binning block
#define EPT 32             // edges per thread in binning (BIN_CHUNK/256)
#define BIN_BLOCKS ((N_EDGES + BIN_CHUNK - 1) / BIN_CHUNK)  // 196
#define GEMM1_BLOCKS (N_NODES / 16)                         // 6250
#define WTS 68             // padded stride (floats) of transposed w2 rows
#define LS 136             // padded LDS stride (ushorts) for bf16 A tile (272 B)
#define STH 512            // sort2 threads per block

typedef __attribute__((ext_vector_type(8))) short short8;
typedef __attribute__((ext_vector_type(4))) float f32x4;

__device__ __forceinline__ ushort f2bf(float x) {
    unsigned u = __float_as_uint(x);
    u += 0x7FFFu + ((u >> 16) & 1u);  // round to nearest even
    return (ushort)(u >> 16);
}

// ---------------------------------------------------------------------------
// init: zero bcur; pre-transpose w1 -> bf16 w1t[64][128]; w2 -> f32 w2t[64][68].
// One tiny block; runs once per launch before everything else.
// ---------------------------------------------------------------------------
__global__ __launch_bounds__(256) void init_kernel(const float* __restrict__ w1,
                                                   const float* __restrict__ w2,
                                                   int* __restrict__ bcur,
                                                   ushort* __restrict__ w1t,
                                                   float* __restrict__ w2t) {
    const int tid = threadIdx.x;
    for (int i = tid; i < NB; i += 256) bcur[i] = 0;
    // w1t[c][k] = bf16(w1[k][c])
    for (int i = tid; i < OUT_FEAT * IN_FEAT; i += 256) {
        const int c = i >> 7, k = i & 127;
        w1t[i] = f2bf(w1[(size_t)k * OUT_FEAT + c]);
    }
    // w2t[c][k] (stride WTS) = w2[k][c]
    for (int i = tid; i < OUT_FEAT * WTS; i += 256) {
        const int c = i / WTS, k = i - c * WTS;
        w2t[i] = (k < OUT_FEAT) ? w2[(size_t)k * OUT_FEAT + c] : 0.f;
    }
}

// ---------------------------------------------------------------------------
// Fat kernel: blocks [0, BIN_BLOCKS) do edge binning (latency-bound, hides
// under gemm1); the rest do gemm1 via MFMA bf16.
// gemm1: 16 rows x 64 cols, K=128; A staged bf16 in LDS; B fragments loaded
// DIRECTLY from global w1t (16 KB, L1-resident) -> no B staging.
// ---------------------------------------------------------------------------
union FatSmem {
    struct { ushort a[16 * LS]; } g;            // 4.25 KB
    struct { int cnt[NB]; int gbase[NB]; } bb;  // 6.3 KB
};

__global__ __launch_bounds__(256) void gemm1_binning_kernel(
        const float* __restrict__ feat, const ushort* __restrict__ w1t,
        ushort* __restrict__ h1,
        const int* __restrict__ src, const int* __restrict__ dst,
        int* __restrict__ bcur, int* __restrict__ pairs) {
    __shared__ FatSmem s;
    const int tid = threadIdx.x;

    if (blockIdx.x >= BIN_BLOCKS) {
        // ---------------- gemm1 (MFMA): feat[16 rows] @ w1 -> bf16 h1 ----------
        const int row0 = (blockIdx.x - BIN_BLOCKS) * 16;

        // stage A: 16 feat rows f32 -> bf16 LDS [16][LS]
        {
            const float4* fg = (const float4*)(feat + (size_t)row0 * IN_FEAT);
#pragma unroll
            for (int half = 0; half < 2; ++half) {
                const int i = tid + half * 256;   // float4 index, 512 total
                const float4 v = fg[i];
                const int r = i >> 5;             // row
                const int c4 = (i & 31) * 4;      // col of first elem
                ushort* p = s.g.a + r * LS + c4;  // 8B-aligned
                ushort4 u;
                u.x = f2bf(v.x); u.y = f2bf(v.y); u.z = f2bf(v.z); u.w = f2bf(v.w);
                *(ushort4*)p = u;
            }
        }
        __syncthreads();

        const int w = tid >> 6;    // wave -> 16-col slice
        const int l = tid & 63;    // lane
        const int lr = l & 15;     // A row / B col within tile
        const int lk = l >> 4;     // k subgroup (8 elems)

        f32x4 acc = {0.f, 0.f, 0.f, 0.f};
        const char* Ab = (const char*)s.g.a;
        const ushort* Brow = w1t + (w * 16 + lr) * IN_FEAT;  // L1-resident
#pragma unroll
        for (int kk = 0; kk < 4; ++kk) {
            const short8 af = *(const short8*)(Ab + lr * (LS * 2) + kk * 64 + lk * 16);
            const short8 bf = *(const short8*)(Brow + kk * 32 + lk * 8);
            acc = __builtin_amdgcn_mfma_f32_16x16x32_bf16(af, bf, acc, 0, 0, 0);
        }

        // D layout: col = lane&15, row = (lane>>4)*4 + i  [m89-verified]
#pragma unroll
        for (int i = 0; i < 4; ++i) {
            const int row = lk * 4 + i;
            h1[(size_t)(row0 + row) * OUT_FEAT + w * 16 + lr] = f2bf(acc[i]);
        }
    } else {
        // ---------------- binning: dense per-block runs per bucket ----------------
        int* cnt = s.bb.cnt;
        int* gbase = s.bb.gbase;
        for (int i = tid; i < NB; i += 256) cnt[i] = 0;
        __syncthreads();
        const int base = blockIdx.x * BIN_CHUNK;
        int bl[EPT];  // (bucket<<13) | local_rank, or -1
        int vp[EPT];  // packed payload ((dst&127)<<17 | src)
#pragma unroll
        for (int i = 0; i < EPT; ++i) {
            const int e = base + i * 256 + tid;
            if (e < N_EDGES) {
                const int d = dst[e];
                const int b = d >> 7;
                const int lpos = atomicAdd(&cnt[b], 1);
                bl[i] = (b << 13) | lpos;
                vp[i] = ((d & 127) << 17) | src[e];
            } else {
                bl[i] = -1;
            }
        }
        __syncthreads();
        for (int i = tid; i < NB; i += 256) {
            const int cc = cnt[i];
            gbase[i] = cc ? (i * CAP + atomicAdd(&bcur[i], cc)) : 0;
        }
        __syncthreads();
#pragma unroll
        for (int i = 0; i < EPT; ++i) {
            if (bl[i] >= 0) {
                const int b = bl[i] >> 13, lpos = bl[i] & 8191;
                pairs[gbase[b] + lpos] = vp[i];
            }
        }
    }
}

// ---------------------------------------------------------------------------
// Per-bucket counting sort -> per-node CSR segments (within static windows).
// 512 threads/block (halves the count/fill chains). csr entries are BYTE
// offsets of the src row (src*128).
// ---------------------------------------------------------------------------
__global__ __launch_bounds__(STH) void sort2_kernel(const int* __restrict__ pairs,
                                                    const int* __restrict__ bcur,
                                                    int* __restrict__ csr,
                                                    int2* __restrict__ nseg) {
    __shared__ int cnt[NPB];
    __shared__ int cur[NPB];
    __shared__ int wtot;
    const int b = blockIdx.x;
    const int t = threadIdx.x;
    const int beg = b * CAP;
    const int end = beg + bcur[b];
    if (t < NPB) cnt[t] = 0;
    __syncthreads();
    for (int i = beg + t; i < end; i += STH)
        atomicAdd(&cnt[pairs[i] >> 17], 1);
    __syncthreads();
    int v = 0, x = 0;
    const int lane = t & 63, w = t >> 6;
    if (t < NPB) {
        v = cnt[t];
        x = v;
#pragma unroll
        for (int off = 1; off < 64; off <<= 1) {
            int y = __shfl_up(x, off);
            if (lane >= off) x += y;
        }
        if (t == 63) wtot = x;
    }
    __syncthreads();
    if (t < NPB) {
        const int gp = beg + (x - v) + (w ? wtot : 0);
        cur[t] = gp;
        nseg[b * NPB + t] = make_int2(gp, gp + v);
    }
    __syncthreads();
    for (int i = beg + t; i < end; i += STH) {
        const int p = pairs[i];
        const int pos = atomicAdd(&cur[p >> 17], 1);
        csr[pos] = (p & 0x1FFFF) << 7;  // byte offset of the src row
    }
}

// ---------------------------------------------------------------------------
// Pair-gather core (round-10 version, measured best): lanes 0-31 read row
// csr[i], lanes 32-63 read row csr[i+1]; each lane loads a uint = 2 bf16
// columns {2cp, 2cp+1}. Caller merges halves with shfl_xor(32).
// ---------------------------------------------------------------------------
__device__ __forceinline__ float2 gather_pairs(const char* __restrict__ hb,
                                               const int* __restrict__ csr,
                                               int beg, int end, int hi, int cp4) {
    float ax = 0.f, ay = 0.f;
    int i = beg;
#define LOADU(k) const unsigned u##k = *(const unsigned*)(hb + (unsigned)(csr[i + 2*(k) + hi] + cp4))
#define ACCU(k)                                            \
    ax += __uint_as_float(u##k << 16);                     \
    ay += __uint_as_float(u##k & 0xFFFF0000u)
    for (; i + 16 <= end; i += 16) {  // 8 pair-rounds = 16 edges
        LOADU(0); LOADU(1); LOADU(2); LOADU(3);
        LOADU(4); LOADU(5); LOADU(6); LOADU(7);
        ACCU(0); ACCU(1); ACCU(2); ACCU(3);
        ACCU(4); ACCU(5); ACCU(6); ACCU(7);
    }
    if (i + 8 <= end) {
        LOADU(0); LOADU(1); LOADU(2); LOADU(3);
        ACCU(0); ACCU(1); ACCU(2); ACCU(3);
        i += 8;
    }
    if (i + 4 <= end) {
        LOADU(0); LOADU(1);
        ACCU(0); ACCU(1);
        i += 4;
    }
    for (; i < end; i += 2) {
        if (i + hi < end) {
            const unsigned u = *(const unsigned*)(hb + (unsigned)(csr[i + hi] + cp4));
            ax += __uint_as_float(u << 16);
            ay += __uint_as_float(u & 0xFFFF0000u);
        }
    }
#undef LOADU
#undef ACCU
    return make_float2(ax, ay);
}

// ---------------------------------------------------------------------------
// Layer-1 fused: agg(h1) -> rrelu -> @w2 -> bf16 h2. One wave per node.
// wt staged from pre-transposed w2t via flat float4 copy (b128 issues).
// ---------------------------------------------------------------------------
__global__ __launch_bounds__(256) void agg_gemm2_kernel(const ushort* __restrict__ h,
                                                        const int* __restrict__ csr,
                                                        const int2* __restrict__ nseg,
                                                        const float* __restrict__ w2t,
                                                        ushort* __restrict__ h2) {
    __shared__ float wt[OUT_FEAT * WTS];   // 17 KB transposed w2
    __shared__ float rowbuf[4][OUT_FEAT];  // 1 KB, one row per wave
    const int tid = threadIdx.x;
    const int c = tid & 63;

    // stage wt: flat copy of w2t (4352 floats = 1088 float4)
    {
        const float4* g4 = (const float4*)w2t;
        float4* l4 = (float4*)wt;
#pragma unroll
        for (int j = 0; j < 4; ++j) l4[tid + j * 256] = g4[tid + j * 256];
        if (tid < 64) l4[1024 + tid] = g4[1024 + tid];
    }
    __syncthreads();  // wt staged (only cross-wave dependency)

    const int wv = tid >> 6;
    const int hi = (tid >> 5) & 1, cp = tid & 31;
    const int node = blockIdx.x * 4 + wv;  // grid = 25000, all valid
    const int2 seg = nseg[node];
    const int beg = __builtin_amdgcn_readfirstlane(seg.x);
    const int end = __builtin_amdgcn_readfirstlane(seg.y);

    float2 acc = gather_pairs((const char*)h, csr, beg, end, hi, cp * 4);
    acc.x += __shfl_xor(acc.x, 32);
    acc.y += __shfl_xor(acc.y, 32);
    acc.x = acc.x >= 0.f ? acc.x : acc.x * SLOPE;
    acc.y = acc.y >= 0.f ? acc.y : acc.y * SLOPE;

    // stage the node's row (intra-wave only; no block barrier needed)
    if (hi == 0) ((float2*)rowbuf[wv])[cp] = acc;

    float o = 0.f;
    const float4* rb4 = (const float4*)rowbuf[wv];
    const float4* wt4 = (const float4*)(wt + c * WTS);  // 272B stride, 16B-aligned
#pragma unroll
    for (int j4 = 0; j4 < 16; ++j4) {
        const float4 r = rb4[j4];  // wave-uniform broadcast
        const float4 v = wt4[j4];  // b128
        o += r.x * v.x + r.y * v.y + r.z * v.z + r.w * v.w;
    }
    h2[(size_t)node * OUT_FEAT + c] = f2bf(o);
}

// ---------------------------------------------------------------------------
// Layer-2 aggregation + fused rrelu -> f32 d_out. One wave per node.
// ---------------------------------------------------------------------------
__global__ __launch_bounds__(256) void agg_rrelu_kernel(const ushort* __restrict__ h,
                                                        const int* __restrict__ csr,
                                                        const int2* __restrict__ nseg,
                                                        float* __restrict__ out) {
    const int tid = threadIdx.x;
    const int hi = (tid >> 5) & 1, cp = tid & 31;
    const int node = blockIdx.x * 4 + (tid >> 6);
    const int2 seg = nseg[node];
    const int beg = __builtin_amdgcn_readfirstlane(seg.x);
    const int end = __builtin_amdgcn_readfirstlane(seg.y);

    float2 acc = gather_pairs((const char*)h, csr, beg, end, hi, cp * 4);
    acc.x += __shfl_xor(acc.x, 32);
    acc.y += __shfl_xor(acc.y, 32);
    if (hi == 0) {
        acc.x = acc.x >= 0.f ? acc.x : acc.x * SLOPE;
        acc.y = acc.y >= 0.f ? acc.y : acc.y * SLOPE;
        ((float2*)(out + (size_t)node * OUT_FEAT))[cp] = acc;
    }
}

extern "C" void kernel_launch(void* const* d_in, const int* in_sizes, int n_in,
                              void* d_out, int out_size, void* d_ws, size_t ws_size,
                              hipStream_t stream) {
    const float* feat = (const float*)d_in[0];
    const int*   src  = (const int*)d_in[1];
    const int*   dst  = (const int*)d_in[2];
    const float* w1   = (const float*)d_in[3];
    const float* w2   = (const float*)d_in[4];
    float* out = (float*)d_out;

    // workspace layout (pairs aliases h2: pairs is dead before h2 is written)
    ushort* h1   = (ushort*)d_ws;                             // 12.8 MB
    ushort* h2   = h1 + (size_t)N_NODES * OUT_FEAT;           // 12.8 MB
    int*    pairs = (int*)h2;                                 // 6.4 MB (alias)
    int*    csr  = (int*)(h2 + (size_t)N_NODES * OUT_FEAT);   // NB*CAP = 8.0 MB
    int2*   nseg = (int2*)(csr + NB * CAP);                   // 0.8 MB
    int*    bcur = (int*)(nseg + NB * NPB);                   // NB ints
    ushort* w1t  = (ushort*)(bcur + NB);                      // 16 KB
    float*  w2t  = (float*)(w1t + OUT_FEAT * IN_FEAT);        // 17.4 KB

    // ---- init (bcur zero + weight pre-transposes) ----
    init_kernel<<<1, 256, 0, stream>>>(w1, w2, bcur, w1t, w2t);

    // ---- [gemm1 || binning] fat (binning hides under gemm1), then sort2 ----
    gemm1_binning_kernel<<<BIN_BLOCKS + GEMM1_BLOCKS, 256, 0, stream>>>(
        feat, w1t, h1, src, dst, bcur, pairs);
    sort2_kernel<<<NB, STH, 0, stream>>>(pairs, bcur, csr, nseg);

    // ---- layer 1 (gemm2 fused into aggregation) ----
    agg_gemm2_kernel<<<N_NODES / 4, 256, 0, stream>>>(h1, csr, nseg, w2t, h2);

    // ---- layer 2 ----
    agg_rrelu_kernel<<<N_NODES / 4, 256, 0, stream>>>(h2, csr, nseg, out);
}

// Round 18
// 150.995 us; speedup vs baseline: 1.0643x; 1.0643x over previous
//
#include <hip/hip_runtime.h>

#define N_NODES 100000
#define N_EDGES 1600000
#define IN_FEAT 128
#define OUT_FEAT 64
#define SLOPE 0.22916666666666666f  // (1/8 + 1/3)/2 = 11/48

#define NPB 128            // nodes per bucket
#define NB 782             // ceil(N_NODES / NPB)
#define CAP 2560           // static bucket capacity (mean 2046 -> 11+ sigma margin)
#define BIN_CHUNK 4096     // edges per binning block (halved: 2x block parallelism)
#define EPT 16             // edges per thread in binning (BIN_CHUNK/256)
#define BIN_BLOCKS ((N_EDGES + BIN_CHUNK - 1) / BIN_CHUNK)  // 391
#define GEMM1_BLOCKS (N_NODES / 16)                         // 6250
#define WTS 68             // padded stride (floats) of transposed w2 rows
#define LS 136             // padded LDS stride (ushorts) for bf16 tiles (272 B)

typedef __attribute__((ext_vector_type(8))) short short8;
typedef __attribute__((ext_vector_type(4))) float f32x4;

__device__ __forceinline__ ushort f2bf(float x) {
    unsigned u = __float_as_uint(x);
    u += 0x7FFFu + ((u >> 16) & 1u);  // round to nearest even
    return (ushort)(u >> 16);
}

// ---------------------------------------------------------------------------
// Fat kernel: blocks [0, BIN_BLOCKS) do edge binning (latency-bound, hides
// under gemm1); the rest do gemm1 via MFMA bf16 (r16 layout, measured best).
// ---------------------------------------------------------------------------
union FatSmem {
    struct { ushort a[16 * LS]; ushort b[64 * LS]; } g;  // 4.25 + 17 KB
    struct { int cnt[NB]; int gbase[NB]; } bb;           // 6.3 KB
};

__global__ __launch_bounds__(256) void gemm1_binning_kernel(
        const float* __restrict__ feat, const float* __restrict__ w1,
        ushort* __restrict__ h1,
        const int* __restrict__ src, const int* __restrict__ dst,
        int* __restrict__ bcur, int* __restrict__ pairs) {
    __shared__ FatSmem s;
    const int tid = threadIdx.x;

    if (blockIdx.x >= BIN_BLOCKS) {
        // ---------------- gemm1 (MFMA): feat[16 rows] @ w1 -> bf16 h1 ----------
        const int row0 = (blockIdx.x - BIN_BLOCKS) * 16;

        // stage A: 16 feat rows f32 -> bf16 LDS [16][LS]
        {
            const float4* fg = (const float4*)(feat + (size_t)row0 * IN_FEAT);
#pragma unroll
            for (int half = 0; half < 2; ++half) {
                const int i = tid + half * 256;   // float4 index, 512 total
                const float4 v = fg[i];
                const int r = i >> 5;             // row
                const int c4 = (i & 31) * 4;      // col of first elem
                ushort* p = s.g.a + r * LS + c4;  // 8B-aligned
                ushort4 u;
                u.x = f2bf(v.x); u.y = f2bf(v.y); u.z = f2bf(v.z); u.w = f2bf(v.w);
                *(ushort4*)p = u;
            }
        }
        // stage B: w1 [128][64] f32 -> bf16 transposed LDS [64][LS]
        {
            const int c = tid & 63;   // w1 column
            const int kb = tid >> 6;  // k block of 32
#pragma unroll
            for (int j2 = 0; j2 < 16; ++j2) {
                const int k = kb * 32 + j2 * 2;
                const float lo = w1[(size_t)k * OUT_FEAT + c];        // coalesced
                const float hi = w1[(size_t)(k + 1) * OUT_FEAT + c];  // coalesced
                const unsigned pk = (unsigned)f2bf(lo) | ((unsigned)f2bf(hi) << 16);
                *(unsigned*)(s.g.b + c * LS + k) = pk;  // 4B-aligned
            }
        }
        __syncthreads();

        const int w = tid >> 6;    // wave -> 16-col slice
        const int l = tid & 63;    // lane
        const int lr = l & 15;     // A row / B col within tile
        const int lk = l >> 4;     // k subgroup (8 elems)

        f32x4 acc = {0.f, 0.f, 0.f, 0.f};
        const char* Ab = (const char*)s.g.a;
        const char* Bb = (const char*)(s.g.b + (w * 16 + lr) * LS);
#pragma unroll
        for (int kk = 0; kk < 4; ++kk) {
            const short8 af = *(const short8*)(Ab + lr * (LS * 2) + kk * 64 + lk * 16);
            const short8 bf = *(const short8*)(Bb + kk * 64 + lk * 16);
            acc = __builtin_amdgcn_mfma_f32_16x16x32_bf16(af, bf, acc, 0, 0, 0);
        }

        // D layout: col = lane&15, row = (lane>>4)*4 + i  [m89-verified]
#pragma unroll
        for (int i = 0; i < 4; ++i) {
            const int row = lk * 4 + i;
            h1[(size_t)(row0 + row) * OUT_FEAT + w * 16 + lr] = f2bf(acc[i]);
        }
    } else {
        // ---------------- binning: dense per-block runs per bucket ----------------
        int* cnt = s.bb.cnt;
        int* gbase = s.bb.gbase;
        for (int i = tid; i < NB; i += 256) cnt[i] = 0;
        __syncthreads();
        const int base = blockIdx.x * BIN_CHUNK;
        int bl[EPT];  // (bucket<<13) | local_rank, or -1
        int vp[EPT];  // packed payload ((dst&127)<<17 | src)
#pragma unroll
        for (int i = 0; i < EPT; ++i) {
            const int e = base + i * 256 + tid;
            if (e < N_EDGES) {
                const int d = dst[e];
                const int b = d >> 7;
                const int lpos = atomicAdd(&cnt[b], 1);
                bl[i] = (b << 13) | lpos;
                vp[i] = ((d & 127) << 17) | src[e];
            } else {
                bl[i] = -1;
            }
        }
        __syncthreads();
        for (int i = tid; i < NB; i += 256) {
            const int cc = cnt[i];
            gbase[i] = cc ? (i * CAP + atomicAdd(&bcur[i], cc)) : 0;
        }
        __syncthreads();
#pragma unroll
        for (int i = 0; i < EPT; ++i) {
            if (bl[i] >= 0) {
                const int b = bl[i] >> 13, lpos = bl[i] & 8191;
                pairs[gbase[b] + lpos] = vp[i];
            }
        }
    }
}

// ---------------------------------------------------------------------------
// Per-bucket counting sort -> per-node CSR segments (within static windows).
// csr entries are BYTE offsets of the src row (src*128).
// ---------------------------------------------------------------------------
__global__ __launch_bounds__(256) void sort2_kernel(const int* __restrict__ pairs,
                                                    const int* __restrict__ bcur,
                                                    int* __restrict__ csr,
                                                    int2* __restrict__ nseg) {
    __shared__ int cnt[NPB];
    __shared__ int cur[NPB];
    __shared__ int wtot;
    const int b = blockIdx.x;
    const int t = threadIdx.x;
    const int beg = b * CAP;
    const int end = beg + bcur[b];
    if (t < NPB) cnt[t] = 0;
    __syncthreads();
    for (int i = beg + t; i < end; i += 256)
        atomicAdd(&cnt[pairs[i] >> 17], 1);
    __syncthreads();
    int v = 0, x = 0;
    const int lane = t & 63, w = t >> 6;
    if (t < NPB) {
        v = cnt[t];
        x = v;
#pragma unroll
        for (int off = 1; off < 64; off <<= 1) {
            int y = __shfl_up(x, off);
            if (lane >= off) x += y;
        }
        if (t == 63) wtot = x;
    }
    __syncthreads();
    if (t < NPB) {
        const int gp = beg + (x - v) + (w ? wtot : 0);
        cur[t] = gp;
        nseg[b * NPB + t] = make_int2(gp, gp + v);
    }
    __syncthreads();
    for (int i = beg + t; i < end; i += 256) {
        const int p = pairs[i];
        const int pos = atomicAdd(&cur[p >> 17], 1);
        csr[pos] = (p & 0x1FFFF) << 7;  // byte offset of the src row
    }
}

// ---------------------------------------------------------------------------
// Pair-gather core (round-10 version, measured best): lanes 0-31 read row
// csr[i], lanes 32-63 read row csr[i+1]; each lane loads a uint = 2 bf16
// columns {2cp, 2cp+1}. Caller merges halves with shfl_xor(32).
// ---------------------------------------------------------------------------
__device__ __forceinline__ float2 gather_pairs(const char* __restrict__ hb,
                                               const int* __restrict__ csr,
                                               int beg, int end, int hi, int cp4) {
    float ax = 0.f, ay = 0.f;
    int i = beg;
#define LOADU(k) const unsigned u##k = *(const unsigned*)(hb + (unsigned)(csr[i + 2*(k) + hi] + cp4))
#define ACCU(k)                                            \
    ax += __uint_as_float(u##k << 16);                     \
    ay += __uint_as_float(u##k & 0xFFFF0000u)
    for (; i + 16 <= end; i += 16) {  // 8 pair-rounds = 16 edges
        LOADU(0); LOADU(1); LOADU(2); LOADU(3);
        LOADU(4); LOADU(5); LOADU(6); LOADU(7);
        ACCU(0); ACCU(1); ACCU(2); ACCU(3);
        ACCU(4); ACCU(5); ACCU(6); ACCU(7);
    }
    if (i + 8 <= end) {
        LOADU(0); LOADU(1); LOADU(2); LOADU(3);
        ACCU(0); ACCU(1); ACCU(2); ACCU(3);
        i += 8;
    }
    if (i + 4 <= end) {
        LOADU(0); LOADU(1);
        ACCU(0); ACCU(1);
        i += 4;
    }
    for (; i < end; i += 2) {
        if (i + hi < end) {
            const unsigned u = *(const unsigned*)(hb + (unsigned)(csr[i + hi] + cp4));
            ax += __uint_as_float(u << 16);
            ay += __uint_as_float(u & 0xFFFF0000u);
        }
    }
#undef LOADU
#undef ACCU
    return make_float2(ax, ay);
}

// ---------------------------------------------------------------------------
// Layer-1 fused: agg(h1) -> rrelu -> @w2 -> bf16 h2. One wave per node.
// w2 staged TRANSPOSED in LDS (pad-stride 68 floats) -> b128 tail.
// ---------------------------------------------------------------------------
__global__ __launch_bounds__(256) void agg_gemm2_kernel(const ushort* __restrict__ h,
                                                        const int* __restrict__ csr,
                                                        const int2* __restrict__ nseg,
                                                        const float* __restrict__ w2,
                                                        ushort* __restrict__ h2) {
    __shared__ float wt[OUT_FEAT * WTS];   // 17 KB transposed w2
    __shared__ float rowbuf[4][OUT_FEAT];  // 1 KB, one row per wave
    const int tid = threadIdx.x;
    const int c = tid & 63;

    // stage w2 transposed: wave kb covers k = kb*16 .. kb*16+15 for all c
    {
        const int kb = tid >> 6;
#pragma unroll
        for (int j = 0; j < 16; ++j) {
            const int k = kb * 16 + j;
            wt[c * WTS + k] = w2[k * OUT_FEAT + c];  // coalesced 256B per j
        }
    }
    __syncthreads();  // wt staged (only cross-wave dependency)

    const int wv = tid >> 6;
    const int hi = (tid >> 5) & 1, cp = tid & 31;
    const int node = blockIdx.x * 4 + wv;  // grid = 25000, all valid
    const int2 seg = nseg[node];
    const int beg = __builtin_amdgcn_readfirstlane(seg.x);
    const int end = __builtin_amdgcn_readfirstlane(seg.y);

    float2 acc = gather_pairs((const char*)h, csr, beg, end, hi, cp * 4);
    acc.x += __shfl_xor(acc.x, 32);
    acc.y += __shfl_xor(acc.y, 32);
    acc.x = acc.x >= 0.f ? acc.x : acc.x * SLOPE;
    acc.y = acc.y >= 0.f ? acc.y : acc.y * SLOPE;

    // stage the node's row (intra-wave only; no block barrier needed)
    if (hi == 0) ((float2*)rowbuf[wv])[cp] = acc;

    float o = 0.f;
    const float4* rb4 = (const float4*)rowbuf[wv];
    const float4* wt4 = (const float4*)(wt + c * WTS);  // 272B stride, 16B-aligned
#pragma unroll
    for (int j4 = 0; j4 < 16; ++j4) {
        const float4 r = rb4[j4];  // wave-uniform broadcast
        const float4 v = wt4[j4];  // b128
        o += r.x * v.x + r.y * v.y + r.z * v.z + r.w * v.w;
    }
    h2[(size_t)node * OUT_FEAT + c] = f2bf(o);
}

// ---------------------------------------------------------------------------
// Layer-2 aggregation + fused rrelu -> f32 d_out. One wave per node.
// ---------------------------------------------------------------------------
__global__ __launch_bounds__(256) void agg_rrelu_kernel(const ushort* __restrict__ h,
                                                        const int* __restrict__ csr,
                                                        const int2* __restrict__ nseg,
                                                        float* __restrict__ out) {
    const int tid = threadIdx.x;
    const int hi = (tid >> 5) & 1, cp = tid & 31;
    const int node = blockIdx.x * 4 + (tid >> 6);
    const int2 seg = nseg[node];
    const int beg = __builtin_amdgcn_readfirstlane(seg.x);
    const int end = __builtin_amdgcn_readfirstlane(seg.y);

    float2 acc = gather_pairs((const char*)h, csr, beg, end, hi, cp * 4);
    acc.x += __shfl_xor(acc.x, 32);
    acc.y += __shfl_xor(acc.y, 32);
    if (hi == 0) {
        acc.x = acc.x >= 0.f ? acc.x : acc.x * SLOPE;
        acc.y = acc.y >= 0.f ? acc.y : acc.y * SLOPE;
        ((float2*)(out + (size_t)node * OUT_FEAT))[cp] = acc;
    }
}

extern "C" void kernel_launch(void* const* d_in, const int* in_sizes, int n_in,
                              void* d_out, int out_size, void* d_ws, size_t ws_size,
                              hipStream_t stream) {
    const float* feat = (const float*)d_in[0];
    const int*   src  = (const int*)d_in[1];
    const int*   dst  = (const int*)d_in[2];
    const float* w1   = (const float*)d_in[3];
    const float* w2   = (const float*)d_in[4];
    float* out = (float*)d_out;

    // workspace layout (pairs aliases h2: pairs is dead before h2 is written)
    ushort* h1   = (ushort*)d_ws;                             // 12.8 MB
    ushort* h2   = h1 + (size_t)N_NODES * OUT_FEAT;           // 12.8 MB
    int*    pairs = (int*)h2;                                 // 6.4 MB (alias)
    int*    csr  = (int*)(h2 + (size_t)N_NODES * OUT_FEAT);   // NB*CAP = 8.0 MB
    int2*   nseg = (int2*)(csr + NB * CAP);                   // 0.8 MB
    int*    bcur = (int*)(nseg + NB * NPB);                   // NB

    // ---- [gemm1 || binning] fat (binning hides under gemm1), then sort2 ----
    hipMemsetAsync(bcur, 0, NB * sizeof(int), stream);
    gemm1_binning_kernel<<<BIN_BLOCKS + GEMM1_BLOCKS, 256, 0, stream>>>(
        feat, w1, h1, src, dst, bcur, pairs);
    sort2_kernel<<<NB, 256, 0, stream>>>(pairs, bcur, csr, nseg);

    // ---- layer 1 (gemm2 fused into aggregation) ----
    agg_gemm2_kernel<<<N_NODES / 4, 256, 0, stream>>>(h1, csr, nseg, w2, h2);

    // ---- layer 2 ----
    agg_rrelu_kernel<<<N_NODES / 4, 256, 0, stream>>>(h2, csr, nseg, out);
}

// Round 19
// 150.750 us; speedup vs baseline: 1.0661x; 1.0016x over previous
//
#include <hip/hip_runtime.h>

#define N_NODES 100000
#define N_EDGES 1600000
#define IN_FEAT 128
#define OUT_FEAT 64
#define SLOPE 0.22916666666666666f  // (1/8 + 1/3)/2 = 11/48

#define NPB 128            // nodes per bucket
#define NB 782             // ceil(N_NODES / NPB)
#define CAP 2560           // static bucket capacity (mean 2046 -> 11+ sigma margin)
#define BIN_CHUNK 4096     // edges per binning block (halved: 2x block parallelism)
#define EPT 16             // edges per thread in binning (BIN_CHUNK/256)
#define BIN_BLOCKS ((N_EDGES + BIN_CHUNK - 1) / BIN_CHUNK)  // 391
#define GEMM1_BLOCKS (N_NODES / 16)                         // 6250
#define WTS 68             // padded stride (floats) of transposed w2 rows
#define LS 136             // padded LDS stride (ushorts) for bf16 tiles (272 B)

typedef __attribute__((ext_vector_type(8))) short short8;
typedef __attribute__((ext_vector_type(4))) float f32x4;

__device__ __forceinline__ ushort f2bf(float x) {
    unsigned u = __float_as_uint(x);
    u += 0x7FFFu + ((u >> 16) & 1u);  // round to nearest even
    return (ushort)(u >> 16);
}

// ---------------------------------------------------------------------------
// Fat kernel: blocks [0, BIN_BLOCKS) do edge binning (latency-bound, hides
// under gemm1); the rest do gemm1 via MFMA bf16 (r16 layout, measured best).
// ---------------------------------------------------------------------------
union FatSmem {
    struct { ushort a[16 * LS]; ushort b[64 * LS]; } g;  // 4.25 + 17 KB
    struct { int cnt[NB]; int gbase[NB]; } bb;           // 6.3 KB
};

__global__ __launch_bounds__(256) void gemm1_binning_kernel(
        const float* __restrict__ feat, const float* __restrict__ w1,
        ushort* __restrict__ h1,
        const int* __restrict__ src, const int* __restrict__ dst,
        int* __restrict__ bcur, int* __restrict__ pairs) {
    __shared__ FatSmem s;
    const int tid = threadIdx.x;

    if (blockIdx.x >= BIN_BLOCKS) {
        // ---------------- gemm1 (MFMA): feat[16 rows] @ w1 -> bf16 h1 ----------
        const int row0 = (blockIdx.x - BIN_BLOCKS) * 16;

        // stage A: 16 feat rows f32 -> bf16 LDS [16][LS]
        {
            const float4* fg = (const float4*)(feat + (size_t)row0 * IN_FEAT);
#pragma unroll
            for (int half = 0; half < 2; ++half) {
                const int i = tid + half * 256;   // float4 index, 512 total
                const float4 v = fg[i];
                const int r = i >> 5;             // row
                const int c4 = (i & 31) * 4;      // col of first elem
                ushort* p = s.g.a + r * LS + c4;  // 8B-aligned
                ushort4 u;
                u.x = f2bf(v.x); u.y = f2bf(v.y); u.z = f2bf(v.z); u.w = f2bf(v.w);
                *(ushort4*)p = u;
            }
        }
        // stage B: w1 [128][64] f32 -> bf16 transposed LDS [64][LS]
        {
            const int c = tid & 63;   // w1 column
            const int kb = tid >> 6;  // k block of 32
#pragma unroll
            for (int j2 = 0; j2 < 16; ++j2) {
                const int k = kb * 32 + j2 * 2;
                const float lo = w1[(size_t)k * OUT_FEAT + c];        // coalesced
                const float hi = w1[(size_t)(k + 1) * OUT_FEAT + c];  // coalesced
                const unsigned pk = (unsigned)f2bf(lo) | ((unsigned)f2bf(hi) << 16);
                *(unsigned*)(s.g.b + c * LS + k) = pk;  // 4B-aligned
            }
        }
        __syncthreads();

        const int w = tid >> 6;    // wave -> 16-col slice
        const int l = tid & 63;    // lane
        const int lr = l & 15;     // A row / B col within tile
        const int lk = l >> 4;     // k subgroup (8 elems)

        f32x4 acc = {0.f, 0.f, 0.f, 0.f};
        const char* Ab = (const char*)s.g.a;
        const char* Bb = (const char*)(s.g.b + (w * 16 + lr) * LS);
#pragma unroll
        for (int kk = 0; kk < 4; ++kk) {
            const short8 af = *(const short8*)(Ab + lr * (LS * 2) + kk * 64 + lk * 16);
            const short8 bf = *(const short8*)(Bb + kk * 64 + lk * 16);
            acc = __builtin_amdgcn_mfma_f32_16x16x32_bf16(af, bf, acc, 0, 0, 0);
        }

        // D layout: col = lane&15, row = (lane>>4)*4 + i  [m89-verified]
#pragma unroll
        for (int i = 0; i < 4; ++i) {
            const int row = lk * 4 + i;
            h1[(size_t)(row0 + row) * OUT_FEAT + w * 16 + lr] = f2bf(acc[i]);
        }
    } else {
        // ---------------- binning: dense per-block runs per bucket ----------------
        int* cnt = s.bb.cnt;
        int* gbase = s.bb.gbase;
        for (int i = tid; i < NB; i += 256) cnt[i] = 0;
        __syncthreads();
        const int base = blockIdx.x * BIN_CHUNK;
        int bl[EPT];  // (bucket<<13) | local_rank, or -1
        int vp[EPT];  // packed payload ((dst&127)<<17 | src)
#pragma unroll
        for (int i = 0; i < EPT; ++i) {
            const int e = base + i * 256 + tid;
            if (e < N_EDGES) {
                const int d = dst[e];
                const int b = d >> 7;
                const int lpos = atomicAdd(&cnt[b], 1);
                bl[i] = (b << 13) | lpos;
                vp[i] = ((d & 127) << 17) | src[e];
            } else {
                bl[i] = -1;
            }
        }
        __syncthreads();
        for (int i = tid; i < NB; i += 256) {
            const int cc = cnt[i];
            gbase[i] = cc ? (i * CAP + atomicAdd(&bcur[i], cc)) : 0;
        }
        __syncthreads();
#pragma unroll
        for (int i = 0; i < EPT; ++i) {
            if (bl[i] >= 0) {
                const int b = bl[i] >> 13, lpos = bl[i] & 8191;
                pairs[gbase[b] + lpos] = vp[i];
            }
        }
    }
}

// ---------------------------------------------------------------------------
// Per-bucket counting sort -> per-node CSR segments (within static windows).
// csr entries are BYTE offsets of the src row (src*128).
// ---------------------------------------------------------------------------
__global__ __launch_bounds__(256) void sort2_kernel(const int* __restrict__ pairs,
                                                    const int* __restrict__ bcur,
                                                    int* __restrict__ csr,
                                                    int2* __restrict__ nseg) {
    __shared__ int cnt[NPB];
    __shared__ int cur[NPB];
    __shared__ int wtot;
    const int b = blockIdx.x;
    const int t = threadIdx.x;
    const int beg = b * CAP;
    const int end = beg + bcur[b];
    if (t < NPB) cnt[t] = 0;
    __syncthreads();
    for (int i = beg + t; i < end; i += 256)
        atomicAdd(&cnt[pairs[i] >> 17], 1);
    __syncthreads();
    int v = 0, x = 0;
    const int lane = t & 63, w = t >> 6;
    if (t < NPB) {
        v = cnt[t];
        x = v;
#pragma unroll
        for (int off = 1; off < 64; off <<= 1) {
            int y = __shfl_up(x, off);
            if (lane >= off) x += y;
        }
        if (t == 63) wtot = x;
    }
    __syncthreads();
    if (t < NPB) {
        const int gp = beg + (x - v) + (w ? wtot : 0);
        cur[t] = gp;
        nseg[b * NPB + t] = make_int2(gp, gp + v);
    }
    __syncthreads();
    for (int i = beg + t; i < end; i += 256) {
        const int p = pairs[i];
        const int pos = atomicAdd(&cur[p >> 17], 1);
        csr[pos] = (p & 0x1FFFF) << 7;  // byte offset of the src row
    }
}

// ---------------------------------------------------------------------------
// Pair-gather core (round-10 version, measured best): lanes 0-31 read row
// csr[i], lanes 32-63 read row csr[i+1]; each lane loads a uint = 2 bf16
// columns {2cp, 2cp+1}. Caller merges halves with shfl_xor(32).
// ---------------------------------------------------------------------------
__device__ __forceinline__ float2 gather_pairs(const char* __restrict__ hb,
                                               const int* __restrict__ csr,
                                               int beg, int end, int hi, int cp4) {
    float ax = 0.f, ay = 0.f;
    int i = beg;
#define LOADU(k) const unsigned u##k = *(const unsigned*)(hb + (unsigned)(csr[i + 2*(k) + hi] + cp4))
#define ACCU(k)                                            \
    ax += __uint_as_float(u##k << 16);                     \
    ay += __uint_as_float(u##k & 0xFFFF0000u)
    for (; i + 16 <= end; i += 16) {  // 8 pair-rounds = 16 edges
        LOADU(0); LOADU(1); LOADU(2); LOADU(3);
        LOADU(4); LOADU(5); LOADU(6); LOADU(7);
        ACCU(0); ACCU(1); ACCU(2); ACCU(3);
        ACCU(4); ACCU(5); ACCU(6); ACCU(7);
    }
    if (i + 8 <= end) {
        LOADU(0); LOADU(1); LOADU(2); LOADU(3);
        ACCU(0); ACCU(1); ACCU(2); ACCU(3);
        i += 8;
    }
    if (i + 4 <= end) {
        LOADU(0); LOADU(1);
        ACCU(0); ACCU(1);
        i += 4;
    }
    for (; i < end; i += 2) {
        if (i + hi < end) {
            const unsigned u = *(const unsigned*)(hb + (unsigned)(csr[i + hi] + cp4));
            ax += __uint_as_float(u << 16);
            ay += __uint_as_float(u & 0xFFFF0000u);
        }
    }
#undef LOADU
#undef ACCU
    return make_float2(ax, ay);
}

// ---------------------------------------------------------------------------
// Layer-1 fused: agg(h1) -> rrelu -> @w2 -> bf16 h2. One wave per node.
// w2 staged TRANSPOSED in LDS (pad-stride 68 floats) -> b128 tail.
// ---------------------------------------------------------------------------
__global__ __launch_bounds__(256) void agg_gemm2_kernel(const ushort* __restrict__ h,
                                                        const int* __restrict__ csr,
                                                        const int2* __restrict__ nseg,
                                                        const float* __restrict__ w2,
                                                        ushort* __restrict__ h2) {
    __shared__ float wt[OUT_FEAT * WTS];   // 17 KB transposed w2
    __shared__ float rowbuf[4][OUT_FEAT];  // 1 KB, one row per wave
    const int tid = threadIdx.x;
    const int c = tid & 63;

    // stage w2 transposed: wave kb covers k = kb*16 .. kb*16+15 for all c
    {
        const int kb = tid >> 6;
#pragma unroll
        for (int j = 0; j < 16; ++j) {
            const int k = kb * 16 + j;
            wt[c * WTS + k] = w2[k * OUT_FEAT + c];  // coalesced 256B per j
        }
    }
    __syncthreads();  // wt staged (only cross-wave dependency)

    const int wv = tid >> 6;
    const int hi = (tid >> 5) & 1, cp = tid & 31;
    const int node = blockIdx.x * 4 + wv;  // grid = 25000, all valid
    const int2 seg = nseg[node];
    const int beg = __builtin_amdgcn_readfirstlane(seg.x);
    const int end = __builtin_amdgcn_readfirstlane(seg.y);

    float2 acc = gather_pairs((const char*)h, csr, beg, end, hi, cp * 4);
    acc.x += __shfl_xor(acc.x, 32);
    acc.y += __shfl_xor(acc.y, 32);
    acc.x = acc.x >= 0.f ? acc.x : acc.x * SLOPE;
    acc.y = acc.y >= 0.f ? acc.y : acc.y * SLOPE;

    // stage the node's row (intra-wave only; no block barrier needed)
    if (hi == 0) ((float2*)rowbuf[wv])[cp] = acc;

    float o = 0.f;
    const float4* rb4 = (const float4*)rowbuf[wv];
    const float4* wt4 = (const float4*)(wt + c * WTS);  // 272B stride, 16B-aligned
#pragma unroll
    for (int j4 = 0; j4 < 16; ++j4) {
        const float4 r = rb4[j4];  // wave-uniform broadcast
        const float4 v = wt4[j4];  // b128
        o += r.x * v.x + r.y * v.y + r.z * v.z + r.w * v.w;
    }
    h2[(size_t)node * OUT_FEAT + c] = f2bf(o);
}

// ---------------------------------------------------------------------------
// Layer-2 aggregation + fused rrelu -> f32 d_out. One wave per node.
// ---------------------------------------------------------------------------
__global__ __launch_bounds__(256) void agg_rrelu_kernel(const ushort* __restrict__ h,
                                                        const int* __restrict__ csr,
                                                        const int2* __restrict__ nseg,
                                                        float* __restrict__ out) {
    const int tid = threadIdx.x;
    const int hi = (tid >> 5) & 1, cp = tid & 31;
    const int node = blockIdx.x * 4 + (tid >> 6);
    const int2 seg = nseg[node];
    const int beg = __builtin_amdgcn_readfirstlane(seg.x);
    const int end = __builtin_amdgcn_readfirstlane(seg.y);

    float2 acc = gather_pairs((const char*)h, csr, beg, end, hi, cp * 4);
    acc.x += __shfl_xor(acc.x, 32);
    acc.y += __shfl_xor(acc.y, 32);
    if (hi == 0) {
        acc.x = acc.x >= 0.f ? acc.x : acc.x * SLOPE;
        acc.y = acc.y >= 0.f ? acc.y : acc.y * SLOPE;
        ((float2*)(out + (size_t)node * OUT_FEAT))[cp] = acc;
    }
}

extern "C" void kernel_launch(void* const* d_in, const int* in_sizes, int n_in,
                              void* d_out, int out_size, void* d_ws, size_t ws_size,
                              hipStream_t stream) {
    const float* feat = (const float*)d_in[0];
    const int*   src  = (const int*)d_in[1];
    const int*   dst  = (const int*)d_in[2];
    const float* w1   = (const float*)d_in[3];
    const float* w2   = (const float*)d_in[4];
    float* out = (float*)d_out;

    // workspace layout (pairs aliases h2: pairs is dead before h2 is written)
    ushort* h1   = (ushort*)d_ws;                             // 12.8 MB
    ushort* h2   = h1 + (size_t)N_NODES * OUT_FEAT;           // 12.8 MB
    int*    pairs = (int*)h2;                                 // 6.4 MB (alias)
    int*    csr  = (int*)(h2 + (size_t)N_NODES * OUT_FEAT);   // NB*CAP = 8.0 MB
    int2*   nseg = (int2*)(csr + NB * CAP);                   // 0.8 MB
    int*    bcur = (int*)(nseg + NB * NPB);                   // NB

    // ---- [gemm1 || binning] fat (binning hides under gemm1), then sort2 ----
    hipMemsetAsync(bcur, 0, NB * sizeof(int), stream);
    gemm1_binning_kernel<<<BIN_BLOCKS + GEMM1_BLOCKS, 256, 0, stream>>>(
        feat, w1, h1, src, dst, bcur, pairs);
    sort2_kernel<<<NB, 256, 0, stream>>>(pairs, bcur, csr, nseg);

    // ---- layer 1 (gemm2 fused into aggregation) ----
    agg_gemm2_kernel<<<N_NODES / 4, 256, 0, stream>>>(h1, csr, nseg, w2, h2);

    // ---- layer 2 ----
    agg_rrelu_kernel<<<N_NODES / 4, 256, 0, stream>>>(h2, csr, nseg, out);
}

// Round 20
// 147.711 us; speedup vs baseline: 1.0880x; 1.0206x over previous
//
#include <hip/hip_runtime.h>

#define N_NODES 100000
#define N_EDGES 1600000
#define IN_FEAT 128
#define OUT_FEAT 64
#define SLOPE 0.22916666666666666f  // (1/8 + 1/3)/2 = 11/48

#define NPB 128            // nodes per bucket
#define NB 782             // ceil(N_NODES / NPB)
#define CAP 2560           // static bucket capacity (mean 2046 -> 11+ sigma margin)
#define BIN_CHUNK 4096     // edges per binning block
#define EPT 16             // edges per thread in binning (BIN_CHUNK/256)
#define BIN_BLOCKS ((N_EDGES + BIN_CHUNK - 1) / BIN_CHUNK)  // 391
#define GEMM1_ROWS 32      // rows per gemm1 tile (halves block count + w1 traffic)
#define GEMM1_BLOCKS (N_NODES / GEMM1_ROWS)                 // 3125
#define WTS 68             // padded stride (floats) of transposed w2 rows
#define LS 136             // padded LDS stride (ushorts) for bf16 tiles (272 B)
#define STH 512            // sort2 threads per block

typedef __attribute__((ext_vector_type(8))) short short8;
typedef __attribute__((ext_vector_type(4))) float f32x4;

__device__ __forceinline__ ushort f2bf(float x) {
    unsigned u = __float_as_uint(x);
    u += 0x7FFFu + ((u >> 16) & 1u);  // round to nearest even
    return (ushort)(u >> 16);
}

// ---------------------------------------------------------------------------
// Fat kernel: blocks [0, BIN_BLOCKS) do edge binning (latency-bound, hides
// under gemm1); the rest do gemm1 via MFMA bf16 with 32-row tiles.
// ---------------------------------------------------------------------------
union FatSmem {
    struct { ushort a[GEMM1_ROWS * LS]; ushort b[64 * LS]; } g;  // 8.5 + 17 KB
    struct { int cnt[NB]; int gbase[NB]; } bb;                   // 6.3 KB
};

__global__ __launch_bounds__(256) void gemm1_binning_kernel(
        const float* __restrict__ feat, const float* __restrict__ w1,
        ushort* __restrict__ h1,
        const int* __restrict__ src, const int* __restrict__ dst,
        int* __restrict__ bcur, int* __restrict__ pairs) {
    __shared__ FatSmem s;
    const int tid = threadIdx.x;

    if (blockIdx.x >= BIN_BLOCKS) {
        // ------------- gemm1 (MFMA): feat[32 rows] @ w1 -> bf16 h1 -------------
        const int row0 = (blockIdx.x - BIN_BLOCKS) * GEMM1_ROWS;

        // stage A: 32 feat rows f32 -> bf16 LDS [32][LS]
        {
            const float4* fg = (const float4*)(feat + (size_t)row0 * IN_FEAT);
#pragma unroll
            for (int q = 0; q < 4; ++q) {
                const int i = tid + q * 256;      // float4 index, 1024 total
                const float4 v = fg[i];
                const int r = i >> 5;             // row
                const int c4 = (i & 31) * 4;      // col of first elem
                ushort* p = s.g.a + r * LS + c4;  // 8B-aligned
                ushort4 u;
                u.x = f2bf(v.x); u.y = f2bf(v.y); u.z = f2bf(v.z); u.w = f2bf(v.w);
                *(ushort4*)p = u;
            }
        }
        // stage B: w1 [128][64] f32 -> bf16 transposed LDS [64][LS]
        {
            const int c = tid & 63;   // w1 column
            const int kb = tid >> 6;  // k block of 32
#pragma unroll
            for (int j2 = 0; j2 < 16; ++j2) {
                const int k = kb * 32 + j2 * 2;
                const float lo = w1[(size_t)k * OUT_FEAT + c];        // coalesced
                const float hi = w1[(size_t)(k + 1) * OUT_FEAT + c];  // coalesced
                const unsigned pk = (unsigned)f2bf(lo) | ((unsigned)f2bf(hi) << 16);
                *(unsigned*)(s.g.b + c * LS + k) = pk;  // 4B-aligned
            }
        }
        __syncthreads();

        const int w = tid >> 6;    // wave -> 16-col slice
        const int l = tid & 63;    // lane
        const int lr = l & 15;     // A row / B col within tile
        const int lk = l >> 4;     // k subgroup (8 elems)

        f32x4 acc0 = {0.f, 0.f, 0.f, 0.f};
        f32x4 acc1 = {0.f, 0.f, 0.f, 0.f};
        const char* Ab = (const char*)s.g.a;
        const char* Bb = (const char*)(s.g.b + (w * 16 + lr) * LS);
#pragma unroll
        for (int kk = 0; kk < 4; ++kk) {
            const short8 bf = *(const short8*)(Bb + kk * 64 + lk * 16);
            const short8 af0 = *(const short8*)(Ab + lr * (LS * 2) + kk * 64 + lk * 16);
            const short8 af1 =
                *(const short8*)(Ab + (16 + lr) * (LS * 2) + kk * 64 + lk * 16);
            acc0 = __builtin_amdgcn_mfma_f32_16x16x32_bf16(af0, bf, acc0, 0, 0, 0);
            acc1 = __builtin_amdgcn_mfma_f32_16x16x32_bf16(af1, bf, acc1, 0, 0, 0);
        }

        // D layout: col = lane&15, row = (lane>>4)*4 + i  [m89-verified]
#pragma unroll
        for (int i = 0; i < 4; ++i) {
            const int row = lk * 4 + i;
            h1[(size_t)(row0 + row) * OUT_FEAT + w * 16 + lr] = f2bf(acc0[i]);
            h1[(size_t)(row0 + 16 + row) * OUT_FEAT + w * 16 + lr] = f2bf(acc1[i]);
        }
    } else {
        // ---------------- binning: dense per-block runs per bucket ----------------
        int* cnt = s.bb.cnt;
        int* gbase = s.bb.gbase;
        for (int i = tid; i < NB; i += 256) cnt[i] = 0;
        __syncthreads();
        const int base = blockIdx.x * BIN_CHUNK;
        int bl[EPT];  // (bucket<<13) | local_rank, or -1
        int vp[EPT];  // packed payload ((dst&127)<<17 | src)
#pragma unroll
        for (int i = 0; i < EPT; ++i) {
            const int e = base + i * 256 + tid;
            if (e < N_EDGES) {
                const int d = dst[e];
                const int b = d >> 7;
                const int lpos = atomicAdd(&cnt[b], 1);
                bl[i] = (b << 13) | lpos;
                vp[i] = ((d & 127) << 17) | src[e];
            } else {
                bl[i] = -1;
            }
        }
        __syncthreads();
        for (int i = tid; i < NB; i += 256) {
            const int cc = cnt[i];
            gbase[i] = cc ? (i * CAP + atomicAdd(&bcur[i], cc)) : 0;
        }
        __syncthreads();
#pragma unroll
        for (int i = 0; i < EPT; ++i) {
            if (bl[i] >= 0) {
                const int b = bl[i] >> 13, lpos = bl[i] & 8191;
                pairs[gbase[b] + lpos] = vp[i];
            }
        }
    }
}

// ---------------------------------------------------------------------------
// Per-bucket counting sort -> per-node CSR segments (within static windows).
// 512 threads/block (halves count/fill chains). csr entries are BYTE offsets
// of the src row (src*128).
// ---------------------------------------------------------------------------
__global__ __launch_bounds__(STH) void sort2_kernel(const int* __restrict__ pairs,
                                                    const int* __restrict__ bcur,
                                                    int* __restrict__ csr,
                                                    int2* __restrict__ nseg) {
    __shared__ int cnt[NPB];
    __shared__ int cur[NPB];
    __shared__ int wtot;
    const int b = blockIdx.x;
    const int t = threadIdx.x;
    const int beg = b * CAP;
    const int end = beg + bcur[b];
    if (t < NPB) cnt[t] = 0;
    __syncthreads();
    for (int i = beg + t; i < end; i += STH)
        atomicAdd(&cnt[pairs[i] >> 17], 1);
    __syncthreads();
    int v = 0, x = 0;
    const int lane = t & 63, w = t >> 6;
    if (t < NPB) {
        v = cnt[t];
        x = v;
#pragma unroll
        for (int off = 1; off < 64; off <<= 1) {
            int y = __shfl_up(x, off);
            if (lane >= off) x += y;
        }
        if (t == 63) wtot = x;
    }
    __syncthreads();
    if (t < NPB) {
        const int gp = beg + (x - v) + (w ? wtot : 0);
        cur[t] = gp;
        nseg[b * NPB + t] = make_int2(gp, gp + v);
    }
    __syncthreads();
    for (int i = beg + t; i < end; i += STH) {
        const int p = pairs[i];
        const int pos = atomicAdd(&cur[p >> 17], 1);
        csr[pos] = (p & 0x1FFFF) << 7;  // byte offset of the src row
    }
}

// ---------------------------------------------------------------------------
// Pair-gather core (round-10 version, measured best): lanes 0-31 read row
// csr[i], lanes 32-63 read row csr[i+1]; each lane loads a uint = 2 bf16
// columns {2cp, 2cp+1}. Caller merges halves with shfl_xor(32).
// ---------------------------------------------------------------------------
__device__ __forceinline__ float2 gather_pairs(const char* __restrict__ hb,
                                               const int* __restrict__ csr,
                                               int beg, int end, int hi, int cp4) {
    float ax = 0.f, ay = 0.f;
    int i = beg;
#define LOADU(k) const unsigned u##k = *(const unsigned*)(hb + (unsigned)(csr[i + 2*(k) + hi] + cp4))
#define ACCU(k)                                            \
    ax += __uint_as_float(u##k << 16);                     \
    ay += __uint_as_float(u##k & 0xFFFF0000u)
    for (; i + 16 <= end; i += 16) {  // 8 pair-rounds = 16 edges
        LOADU(0); LOADU(1); LOADU(2); LOADU(3);
        LOADU(4); LOADU(5); LOADU(6); LOADU(7);
        ACCU(0); ACCU(1); ACCU(2); ACCU(3);
        ACCU(4); ACCU(5); ACCU(6); ACCU(7);
    }
    if (i + 8 <= end) {
        LOADU(0); LOADU(1); LOADU(2); LOADU(3);
        ACCU(0); ACCU(1); ACCU(2); ACCU(3);
        i += 8;
    }
    if (i + 4 <= end) {
        LOADU(0); LOADU(1);
        ACCU(0); ACCU(1);
        i += 4;
    }
    for (; i < end; i += 2) {
        if (i + hi < end) {
            const unsigned u = *(const unsigned*)(hb + (unsigned)(csr[i + hi] + cp4));
            ax += __uint_as_float(u << 16);
            ay += __uint_as_float(u & 0xFFFF0000u);
        }
    }
#undef LOADU
#undef ACCU
    return make_float2(ax, ay);
}

// ---------------------------------------------------------------------------
// Layer-1 fused: agg(h1) -> rrelu -> @w2 -> bf16 h2. One wave per node.
// w2 staged TRANSPOSED in LDS (pad-stride 68 floats) -> b128 tail.
// ---------------------------------------------------------------------------
__global__ __launch_bounds__(256) void agg_gemm2_kernel(const ushort* __restrict__ h,
                                                        const int* __restrict__ csr,
                                                        const int2* __restrict__ nseg,
                                                        const float* __restrict__ w2,
                                                        ushort* __restrict__ h2) {
    __shared__ float wt[OUT_FEAT * WTS];   // 17 KB transposed w2
    __shared__ float rowbuf[4][OUT_FEAT];  // 1 KB, one row per wave
    const int tid = threadIdx.x;
    const int c = tid & 63;

    // stage w2 transposed: wave kb covers k = kb*16 .. kb*16+15 for all c
    {
        const int kb = tid >> 6;
#pragma unroll
        for (int j = 0; j < 16; ++j) {
            const int k = kb * 16 + j;
            wt[c * WTS + k] = w2[k * OUT_FEAT + c];  // coalesced 256B per j
        }
    }
    __syncthreads();  // wt staged (only cross-wave dependency)

    const int wv = tid >> 6;
    const int hi = (tid >> 5) & 1, cp = tid & 31;
    const int node = blockIdx.x * 4 + wv;  // grid = 25000, all valid
    const int2 seg = nseg[node];
    const int beg = __builtin_amdgcn_readfirstlane(seg.x);
    const int end = __builtin_amdgcn_readfirstlane(seg.y);

    float2 acc = gather_pairs((const char*)h, csr, beg, end, hi, cp * 4);
    acc.x += __shfl_xor(acc.x, 32);
    acc.y += __shfl_xor(acc.y, 32);
    acc.x = acc.x >= 0.f ? acc.x : acc.x * SLOPE;
    acc.y = acc.y >= 0.f ? acc.y : acc.y * SLOPE;

    // stage the node's row (intra-wave only; no block barrier needed)
    if (hi == 0) ((float2*)rowbuf[wv])[cp] = acc;

    float o = 0.f;
    const float4* rb4 = (const float4*)rowbuf[wv];
    const float4* wt4 = (const float4*)(wt + c * WTS);  // 272B stride, 16B-aligned
#pragma unroll
    for (int j4 = 0; j4 < 16; ++j4) {
        const float4 r = rb4[j4];  // wave-uniform broadcast
        const float4 v = wt4[j4];  // b128
        o += r.x * v.x + r.y * v.y + r.z * v.z + r.w * v.w;
    }
    h2[(size_t)node * OUT_FEAT + c] = f2bf(o);
}

// ---------------------------------------------------------------------------
// Layer-2 aggregation + fused rrelu -> f32 d_out. One wave per node.
// ---------------------------------------------------------------------------
__global__ __launch_bounds__(256) void agg_rrelu_kernel(const ushort* __restrict__ h,
                                                        const int* __restrict__ csr,
                                                        const int2* __restrict__ nseg,
                                                        float* __restrict__ out) {
    const int tid = threadIdx.x;
    const int hi = (tid >> 5) & 1, cp = tid & 31;
    const int node = blockIdx.x * 4 + (tid >> 6);
    const int2 seg = nseg[node];
    const int beg = __builtin_amdgcn_readfirstlane(seg.x);
    const int end = __builtin_amdgcn_readfirstlane(seg.y);

    float2 acc = gather_pairs((const char*)h, csr, beg, end, hi, cp * 4);
    acc.x += __shfl_xor(acc.x, 32);
    acc.y += __shfl_xor(acc.y, 32);
    if (hi == 0) {
        acc.x = acc.x >= 0.f ? acc.x : acc.x * SLOPE;
        acc.y = acc.y >= 0.f ? acc.y : acc.y * SLOPE;
        ((float2*)(out + (size_t)node * OUT_FEAT))[cp] = acc;
    }
}

extern "C" void kernel_launch(void* const* d_in, const int* in_sizes, int n_in,
                              void* d_out, int out_size, void* d_ws, size_t ws_size,
                              hipStream_t stream) {
    const float* feat = (const float*)d_in[0];
    const int*   src  = (const int*)d_in[1];
    const int*   dst  = (const int*)d_in[2];
    const float* w1   = (const float*)d_in[3];
    const float* w2   = (const float*)d_in[4];
    float* out = (float*)d_out;

    // workspace layout (pairs aliases h2: pairs is dead before h2 is written)
    ushort* h1   = (ushort*)d_ws;                             // 12.8 MB
    ushort* h2   = h1 + (size_t)N_NODES * OUT_FEAT;           // 12.8 MB
    int*    pairs = (int*)h2;                                 // 6.4 MB (alias)
    int*    csr  = (int*)(h2 + (size_t)N_NODES * OUT_FEAT);   // NB*CAP = 8.0 MB
    int2*   nseg = (int2*)(csr + NB * CAP);                   // 0.8 MB
    int*    bcur = (int*)(nseg + NB * NPB);                   // NB

    // ---- [gemm1 || binning] fat (binning hides under gemm1), then sort2 ----
    hipMemsetAsync(bcur, 0, NB * sizeof(int), stream);
    gemm1_binning_kernel<<<BIN_BLOCKS + GEMM1_BLOCKS, 256, 0, stream>>>(
        feat, w1, h1, src, dst, bcur, pairs);
    sort2_kernel<<<NB, STH, 0, stream>>>(pairs, bcur, csr, nseg);

    // ---- layer 1 (gemm2 fused into aggregation) ----
    agg_gemm2_kernel<<<N_NODES / 4, 256, 0, stream>>>(h1, csr, nseg, w2, h2);

    // ---- layer 2 ----
    agg_rrelu_kernel<<<N_NODES / 4, 256, 0, stream>>>(h2, csr, nseg, out);
}